// Round 3
// baseline (409.120 us; speedup 1.0000x reference)
//
#include <hip/hip_runtime.h>

// Problem constants (reference: T=128, L=32, C=4, B=32, D=512)
#define TT 128
#define LL 32
#define CC 4
#define BB 32
#define DD 512
#define D4 (DD / 4)   // 128 float4 per D-row

__device__ __forceinline__ float4 diff_scale(float4 a, float4 b, float s) {
    return make_float4((a.x - b.x) * s, (a.y - b.y) * s,
                       (a.z - b.z) * s, (a.w - b.w) * s);
}

// ---------------------------------------------------------------------------
// Kernel 1: inclusive prefix sum of f over t, per (b, d4-lane), float4-wide.
// P layout: [B][T+1][D], P[b][0][:]=0, P[b][t+1][:]=sum_{u<=t} f[b][u][:].
// 4096 threads (B*D4), 64/block -> 64 blocks; unroll 16 keeps 16 KB of loads
// in flight per wave.
// ---------------------------------------------------------------------------
__global__ __launch_bounds__(64) void prefix_kernel(const float4* __restrict__ f4,
                                                    float4* __restrict__ P4) {
    int idx = blockIdx.x * 64 + threadIdx.x;   // B*D4 = 4096
    int b = idx >> 7;                           // D4 = 128
    int d4 = idx & (D4 - 1);
    const float4* fp = f4 + (size_t)b * TT * D4 + d4;
    float4* Pp = P4 + (size_t)b * (TT + 1) * D4 + d4;
    float4 acc = make_float4(0.f, 0.f, 0.f, 0.f);
    Pp[0] = acc;
#pragma unroll 16
    for (int t = 0; t < TT; ++t) {
        float4 v = fp[(size_t)t * D4];
        acc.x += v.x; acc.y += v.y; acc.z += v.z; acc.w += v.w;
        Pp[(size_t)(t + 1) * D4] = acc;
    }
}

// ---------------------------------------------------------------------------
// Kernel 2 (fused fc + fm + fb): one block per (b,i), 128 threads = one
// float4 lane of D each. Loop over j: window (i,j) has ws=j-i+1, clip c
// covers frames [4i+c*ws, 4i+(c+1)*ws) -> prefix differences. j<i rows are
// exact zeros. fb[b,i] = (P[4i+4]-P[4i])/4, emitted once per block.
// XCD-aware bijective swizzle: 1024 blocks, XCD k owns b in [4k,4k+4) so
// that b-group's P (~1 MB) stays L2-resident.
// ---------------------------------------------------------------------------
__global__ __launch_bounds__(128) void fused_kernel(const float4* __restrict__ P4,
                                                    const float* __restrict__ mask,
                                                    float4* __restrict__ fc4,
                                                    float4* __restrict__ fm4,
                                                    float4* __restrict__ fb4) {
    int h = blockIdx.x;                          // 0..1023
    int logical = ((h & 7) << 7) | (h >> 3);     // bijective: 1024 % 8 == 0
    int b = logical >> 5;
    int i = logical & (LL - 1);
    int tid = threadIdx.x;                       // d4 lane, 0..127

    const float4* Pb = P4 + (size_t)b * (TT + 1) * D4 + tid;
    size_t base = ((size_t)b * LL + i) * LL;     // flat (b,i,j=0) index
    float4* fcb = fc4 + base * CC * D4 + tid;
    float4* fmb = fm4 + base * D4 + tid;
    const float* mrow = mask + base;

    // Zero rows j < i (Wc identically zero there; d_out is poisoned).
    float4 z = make_float4(0.f, 0.f, 0.f, 0.f);
    for (int j = 0; j < i; ++j) {
        float4* o = fcb + (size_t)j * CC * D4;
        o[0] = z; o[D4] = z; o[2 * D4] = z; o[3 * D4] = z;
        fmb[(size_t)j * D4] = z;
    }

    int s0 = 4 * i;
    float4 p0 = Pb[(size_t)s0 * D4];

    // fb: boundary feature for segment i (free from prefix rows).
    {
        float4 q = Pb[(size_t)(s0 + 4) * D4];
        fb4[((size_t)b * LL + i) * D4 + tid] = diff_scale(q, p0, 0.25f);
    }

    for (int j = i; j < LL; ++j) {
        int ws = j - i + 1;
        float4 p1 = Pb[(size_t)(s0 + ws) * D4];
        float4 p2 = Pb[(size_t)(s0 + 2 * ws) * D4];
        float4 p3 = Pb[(size_t)(s0 + 3 * ws) * D4];
        float4 p4 = Pb[(size_t)(s0 + 4 * ws) * D4];
        float sc = mrow[j] / (float)ws;
        float sm = 0.25f * sc;
        float4* o = fcb + (size_t)j * CC * D4;
        o[0]      = diff_scale(p1, p0, sc);
        o[D4]     = diff_scale(p2, p1, sc);
        o[2 * D4] = diff_scale(p3, p2, sc);
        o[3 * D4] = diff_scale(p4, p3, sc);
        fmb[(size_t)j * D4] = diff_scale(p4, p0, sm);
    }
}

// ---------------------------------------------------------------------------
// Fallback path (workspace too small): direct window sums from f.
// ---------------------------------------------------------------------------
__global__ __launch_bounds__(256) void fcfm_direct(const float* __restrict__ f,
                                                   const float* __restrict__ mask,
                                                   float* __restrict__ fc,
                                                   float* __restrict__ fm) {
    int blk = blockIdx.x;
    int j = blk & (LL - 1);
    int i = (blk >> 5) & (LL - 1);
    int b = blk >> 10;
    int tid = threadIdx.x;
    float* fc_out = fc + (size_t)blk * CC * DD;
    float* fm_out = fm + (size_t)blk * DD;

    if (j < i) {
        float4 z = make_float4(0.f, 0.f, 0.f, 0.f);
        float4* fcv = (float4*)fc_out;
#pragma unroll
        for (int k = 0; k < 2; ++k) fcv[tid + k * 256] = z;
        float4* fmv = (float4*)fm_out;
        if (tid < DD / 4) fmv[tid] = z;
        return;
    }

    int ws = j - i + 1;
    float sc = mask[blk] / (float)ws;
    const float* fbase = f + (size_t)b * TT * DD;

#pragma unroll
    for (int r = 0; r < 2; ++r) {
        int dd = tid + r * 256;
        float tot = 0.f;
#pragma unroll
        for (int c = 0; c < CC; ++c) {
            float s = 0.f;
            int t0 = 4 * i + c * ws;
            for (int t = 0; t < ws; ++t) s += fbase[(size_t)(t0 + t) * DD + dd];
            fc_out[c * DD + dd] = s * sc;
            tot += s;
        }
        fm_out[dd] = tot * sc * 0.25f;
    }
}

__global__ __launch_bounds__(256) void fb_direct(const float* __restrict__ f,
                                                 float* __restrict__ fb) {
    int idx = blockIdx.x * 256 + threadIdx.x;
    int d = idx & (DD - 1);
    int l = (idx >> 9) & (LL - 1);
    int b = idx >> 14;
    const float* fp = f + (size_t)b * TT * DD + d;
    int t0 = 4 * l;
    fb[idx] = (fp[(size_t)t0 * DD] + fp[(size_t)(t0 + 1) * DD] +
               fp[(size_t)(t0 + 2) * DD] + fp[(size_t)(t0 + 3) * DD]) * 0.25f;
}

extern "C" void kernel_launch(void* const* d_in, const int* in_sizes, int n_in,
                              void* d_out, int out_size, void* d_ws, size_t ws_size,
                              hipStream_t stream) {
    const float* f    = (const float*)d_in[0];   // [B,T,D]
    const float* mask = (const float*)d_in[1];   // [B,L,L]
    // d_in[2] = Wc, folded analytically (unused)

    float* out = (float*)d_out;
    const size_t fc_elems = (size_t)BB * LL * LL * CC * DD;   // 67,108,864
    const size_t fm_elems = (size_t)BB * LL * LL * DD;        // 16,777,216
    float* fc = out;
    float* fm = out + fc_elems;
    float* fb = out + fc_elems + fm_elems;

    const size_t P_bytes = (size_t)BB * (TT + 1) * DD * sizeof(float);  // ~8.45 MB

    if (ws_size >= P_bytes) {
        float* P = (float*)d_ws;
        prefix_kernel<<<(BB * D4) / 64, 64, 0, stream>>>((const float4*)f,
                                                         (float4*)P);
        fused_kernel<<<BB * LL, 128, 0, stream>>>((const float4*)P, mask,
                                                  (float4*)fc, (float4*)fm,
                                                  (float4*)fb);
    } else {
        fcfm_direct<<<BB * LL * LL, 256, 0, stream>>>(f, mask, fc, fm);
        fb_direct<<<(BB * LL * DD) / 256, 256, 0, stream>>>(f, fb);
    }
}

// Round 6
// 356.440 us; speedup vs baseline: 1.1478x; 1.1478x over previous
//
#include <hip/hip_runtime.h>

// Problem constants (reference: T=128, L=32, C=4, B=32, D=512)
#define TT 128
#define LL 32
#define CC 4
#define BB 32
#define DD 512
#define D4 (DD / 4)   // 128 float4 per D-row

// Native clang vector type: legal operand for __builtin_nontemporal_store
// (HIP's float4 is a struct wrapper and is rejected by the builtin).
typedef float fx4 __attribute__((ext_vector_type(4)));

__device__ __forceinline__ void nt_store(fx4 v, const fx4* p) {
    __builtin_nontemporal_store(v, (fx4*)p);
}

__device__ __forceinline__ fx4 diff_scale(fx4 a, fx4 b, float s) {
    return (a - b) * s;
}

// ---------------------------------------------------------------------------
// Kernel 1: inclusive prefix sum of f over t, per (b, d4-lane), float4-wide.
// P layout: [B][T+1][D], P[b][0][:]=0, P[b][t+1][:]=sum_{u<=t} f[b][u][:].
// ---------------------------------------------------------------------------
__global__ __launch_bounds__(64) void prefix_kernel(const fx4* __restrict__ f4,
                                                    fx4* __restrict__ P4) {
    int idx = blockIdx.x * 64 + threadIdx.x;   // B*D4 = 4096
    int b = idx >> 7;                           // D4 = 128
    int d4 = idx & (D4 - 1);
    const fx4* fp = f4 + (size_t)b * TT * D4 + d4;
    fx4* Pp = P4 + (size_t)b * (TT + 1) * D4 + d4;
    fx4 acc = (fx4)0.f;
    Pp[0] = acc;
#pragma unroll 16
    for (int t = 0; t < TT; ++t) {
        acc += fp[(size_t)t * D4];
        Pp[(size_t)(t + 1) * D4] = acc;
    }
}

// ---------------------------------------------------------------------------
// Kernel 2: one block per (b,i,j), 128 threads = one float4 lane of D each.
// Window (i,j): ws=j-i+1, clip c covers frames [4i+c*ws, 4i+(c+1)*ws).
//   fc[b,i,j,c,:] = (P[4i+(c+1)ws] - P[4i+c*ws]) * mask/ws
//   fm[b,i,j,:]   = (P[4i+4ws] - P[4i]) * mask/(4ws)
//   fb[b,i,:]     = (P[4i+4] - P[4i]) / 4       (emitted by the j==i block)
// j<i -> exact zeros (Wc rows identically zero; d_out is poisoned).
// Bijective XCD swizzle (32768 blocks % 8 == 0): XCD k gets a contiguous
// chunk of 4096 logical blocks = 4 consecutive b's -> ~1 MB of P per XCD L2.
// All output stores are nontemporal: write-once stream must not evict P.
// ---------------------------------------------------------------------------
__global__ __launch_bounds__(128) void fcfm_kernel(const fx4* __restrict__ P4,
                                                   const float* __restrict__ mask,
                                                   fx4* __restrict__ fc4,
                                                   fx4* __restrict__ fm4,
                                                   fx4* __restrict__ fb4) {
    int h = blockIdx.x;                          // 0..32767
    int blk = ((h & 7) << 12) | (h >> 3);        // (h%8)*4096 + h/8, bijective
    int j = blk & (LL - 1);
    int i = (blk >> 5) & (LL - 1);
    int b = blk >> 10;
    int tid = threadIdx.x;                       // 0..127
    fx4* fc_out = fc4 + (size_t)blk * CC * D4 + tid;
    fx4* fm_out = fm4 + (size_t)blk * D4 + tid;

    if (j < i) {
        fx4 z = (fx4)0.f;
        nt_store(z, fc_out);
        nt_store(z, fc_out + D4);
        nt_store(z, fc_out + 2 * D4);
        nt_store(z, fc_out + 3 * D4);
        nt_store(z, fm_out);
        return;
    }

    int ws = j - i + 1;
    float sc = mask[blk] / (float)ws;
    float sm = 0.25f * sc;
    const fx4* Pb = P4 + (size_t)b * (TT + 1) * D4 + tid;
    int s0 = 4 * i;

    fx4 p0 = Pb[(size_t)(s0) * D4];
    fx4 p1 = Pb[(size_t)(s0 + ws) * D4];
    fx4 p2 = Pb[(size_t)(s0 + 2 * ws) * D4];
    fx4 p3 = Pb[(size_t)(s0 + 3 * ws) * D4];
    fx4 p4 = Pb[(size_t)(s0 + 4 * ws) * D4];

    nt_store(diff_scale(p1, p0, sc), fc_out);
    nt_store(diff_scale(p2, p1, sc), fc_out + D4);
    nt_store(diff_scale(p3, p2, sc), fc_out + 2 * D4);
    nt_store(diff_scale(p4, p3, sc), fc_out + 3 * D4);
    nt_store(diff_scale(p4, p0, sm), fm_out);

    if (j == i) {  // ws==1: p4 = P[4i+4] -> boundary feature is free here
        nt_store(diff_scale(p4, p0, 0.25f),
                 fb4 + ((size_t)b * LL + i) * D4 + tid);
    }
}

// ---------------------------------------------------------------------------
// Fallback path (workspace too small): direct window sums from f.
// ---------------------------------------------------------------------------
__global__ __launch_bounds__(256) void fcfm_direct(const float* __restrict__ f,
                                                   const float* __restrict__ mask,
                                                   float* __restrict__ fc,
                                                   float* __restrict__ fm) {
    int blk = blockIdx.x;
    int j = blk & (LL - 1);
    int i = (blk >> 5) & (LL - 1);
    int b = blk >> 10;
    int tid = threadIdx.x;
    float* fc_out = fc + (size_t)blk * CC * DD;
    float* fm_out = fm + (size_t)blk * DD;

    if (j < i) {
        fx4 z = (fx4)0.f;
        fx4* fcv = (fx4*)fc_out;
#pragma unroll
        for (int k = 0; k < 2; ++k) fcv[tid + k * 256] = z;
        fx4* fmv = (fx4*)fm_out;
        if (tid < DD / 4) fmv[tid] = z;
        return;
    }

    int ws = j - i + 1;
    float sc = mask[blk] / (float)ws;
    const float* fbase = f + (size_t)b * TT * DD;

#pragma unroll
    for (int r = 0; r < 2; ++r) {
        int dd = tid + r * 256;
        float tot = 0.f;
#pragma unroll
        for (int c = 0; c < CC; ++c) {
            float s = 0.f;
            int t0 = 4 * i + c * ws;
            for (int t = 0; t < ws; ++t) s += fbase[(size_t)(t0 + t) * DD + dd];
            fc_out[c * DD + dd] = s * sc;
            tot += s;
        }
        fm_out[dd] = tot * sc * 0.25f;
    }
}

__global__ __launch_bounds__(256) void fb_direct(const float* __restrict__ f,
                                                 float* __restrict__ fb) {
    int idx = blockIdx.x * 256 + threadIdx.x;
    int d = idx & (DD - 1);
    int l = (idx >> 9) & (LL - 1);
    int b = idx >> 14;
    const float* fp = f + (size_t)b * TT * DD + d;
    int t0 = 4 * l;
    fb[idx] = (fp[(size_t)t0 * DD] + fp[(size_t)(t0 + 1) * DD] +
               fp[(size_t)(t0 + 2) * DD] + fp[(size_t)(t0 + 3) * DD]) * 0.25f;
}

extern "C" void kernel_launch(void* const* d_in, const int* in_sizes, int n_in,
                              void* d_out, int out_size, void* d_ws, size_t ws_size,
                              hipStream_t stream) {
    const float* f    = (const float*)d_in[0];   // [B,T,D]
    const float* mask = (const float*)d_in[1];   // [B,L,L]
    // d_in[2] = Wc, folded analytically (unused)

    float* out = (float*)d_out;
    const size_t fc_elems = (size_t)BB * LL * LL * CC * DD;   // 67,108,864
    const size_t fm_elems = (size_t)BB * LL * LL * DD;        // 16,777,216
    float* fc = out;
    float* fm = out + fc_elems;
    float* fb = out + fc_elems + fm_elems;

    const size_t P_bytes = (size_t)BB * (TT + 1) * DD * sizeof(float);  // ~8.45 MB

    if (ws_size >= P_bytes) {
        float* P = (float*)d_ws;
        prefix_kernel<<<(BB * D4) / 64, 64, 0, stream>>>((const fx4*)f,
                                                         (fx4*)P);
        fcfm_kernel<<<BB * LL * LL, 128, 0, stream>>>((const fx4*)P, mask,
                                                      (fx4*)fc, (fx4*)fm,
                                                      (fx4*)fb);
    } else {
        fcfm_direct<<<BB * LL * LL, 256, 0, stream>>>(f, mask, fc, fm);
        fb_direct<<<(BB * LL * DD) / 256, 256, 0, stream>>>(f, fb);
    }
}